// Round 6
// baseline (800.928 us; speedup 1.0000x reference)
//
#include <hip/hip_runtime.h>

// RGCN, 3 layers. N=100000, E=1.6M, R=16, HID=64.
// Edges sorted by (dst,rel) via two-level LDS-bucketed sort (passes A/B).
// md = src(17b) | rel<<20 | segcnt<<24  (cnt = (dst,rel) segment size, <=255).
// Layer kernel: 512-thread blocks (8 waves), 16 nodes/block.
// Phase 1 is now MFMA-based (R1-R5 showed the serial run-length consume was
// a ~50cy/edge dependency chain no pipe could hide):
//   stage A: gather 128 edge rows/chunk into LDS Yt[64][132] (transposed,
//            raw bf16 copy, zero inter-edge deps -> pure MLP).
//   stage B: per node, H^T = Yt @ S^T via mfma_f32_16x16x32_bf16, where
//            S^T[j][r] = (rel_j==r && j in node's range) ? bf16(1/cnt_j) : 0,
//            built in regs from ds_bpermute of the md window. The segmented
//            mean becomes matrix work: no branches, no carried scalar state.
// H layout: per-rel pitch 68 (KD 1088 -> 1152) so stage-B writes spread
// banks; LSTR=1160 (phase-2 A-reads 2-way = free).
// Phase 2 (waves 0-3): out = [H|x] @ Wcat (KD2=1152), as before.

#define HID   64
#define NREL  16
#define RP    68            // padded per-rel pitch in H
#define KD2   1152          // NREL*RP + HID (root x appended as extra K)
#define NPB   16            // nodes per block (= MFMA M)
#define LSTR  1160          // H row stride us16 (residue 4 dw -> 2-way reads)
#define YSTR  132           // Yt row stride us16 (residue 2 dw -> 2-way)
#define CHUNK 128           // edges per staged chunk

#define NBKT  1024          // coarse buckets (dst>>7); requires N <= 131072
#define BSH   7             // bucket shift: 128 nodes per bucket
#define FB    2048          // fine bins per bucket: 128 nodes * 16 rels
#define CAPB  4096          // LDS staging capacity (avg bucket = 2048 edges)
#define CHA   8192          // edges per coarse-pass block

typedef __attribute__((ext_vector_type(8))) short bf16x8;
typedef __attribute__((ext_vector_type(4))) float f32x4;
typedef unsigned short us16;
typedef unsigned int u32;

__device__ __forceinline__ us16 f2b(float f) {   // round-to-nearest-even
    union { float f; u32 i; } c; c.f = f;
    u32 x = c.i;
    return (us16)((x + 0x7FFFu + ((x >> 16) & 1u)) >> 16);
}

// ---------- setup: two-level bucket sort by (dst,rel) ----------

__global__ __launch_bounds__(256) void bucket_count(const int* __restrict__ ei,
                                                    int* __restrict__ counts_b, int E) {
    __shared__ int h[NBKT];
    const int t = threadIdx.x;
    for (int i = t; i < NBKT; i += 256) h[i] = 0;
    __syncthreads();
    const int* dstp = ei + E;
    int start = blockIdx.x * CHA, end = min(start + CHA, E);
    for (int e4 = start + t * 4; e4 < end; e4 += 1024) {
        if (e4 + 3 < end) {
            int4 d = *(const int4*)(dstp + e4);
            atomicAdd(&h[d.x >> BSH], 1);
            atomicAdd(&h[d.y >> BSH], 1);
            atomicAdd(&h[d.z >> BSH], 1);
            atomicAdd(&h[d.w >> BSH], 1);
        } else {
            for (int e = e4; e < end; ++e) atomicAdd(&h[dstp[e] >> BSH], 1);
        }
    }
    __syncthreads();
    for (int i = t; i < NBKT; i += 256) {
        int v = h[i];
        if (v) atomicAdd(&counts_b[i], v);
    }
}

__global__ __launch_bounds__(NBKT) void scan_buckets(const int* __restrict__ counts_b,
                                                     int* __restrict__ bucket_base,
                                                     int* __restrict__ cursor_b,
                                                     int* __restrict__ row_ptr,
                                                     int N, int E) {
    __shared__ int s[NBKT];
    int t = threadIdx.x;
    int v = counts_b[t];
    s[t] = v; __syncthreads();
    for (int off = 1; off < NBKT; off <<= 1) {
        int tv = (t >= off) ? s[t - off] : 0;
        __syncthreads();
        s[t] += tv;
        __syncthreads();
    }
    int ex = s[t] - v;
    bucket_base[t] = ex;
    cursor_b[t] = ex;
    if (t == NBKT - 1) bucket_base[NBKT] = ex + v;
    if (t == 0) row_ptr[N] = E;
}

// packed = src | rel<<17 | dstlow<<21.
__global__ __launch_bounds__(256) void bucket_place(const int* __restrict__ ei,
                                                    const int* __restrict__ et,
                                                    int* __restrict__ cursor_b,
                                                    u32* __restrict__ packed, int E) {
    __shared__ int cnt[NBKT];
    __shared__ int bse[NBKT];
    const int t = threadIdx.x;
    for (int i = t; i < NBKT; i += 256) cnt[i] = 0;
    __syncthreads();
    const int* dstp = ei + E;
    int start = blockIdx.x * CHA, end = min(start + CHA, E);
    for (int e4 = start + t * 4; e4 < end; e4 += 1024) {  // count
        if (e4 + 3 < end) {
            int4 d = *(const int4*)(dstp + e4);
            atomicAdd(&cnt[d.x >> BSH], 1);
            atomicAdd(&cnt[d.y >> BSH], 1);
            atomicAdd(&cnt[d.z >> BSH], 1);
            atomicAdd(&cnt[d.w >> BSH], 1);
        } else {
            for (int e = e4; e < end; ++e) atomicAdd(&cnt[dstp[e] >> BSH], 1);
        }
    }
    __syncthreads();
    for (int i = t; i < NBKT; i += 256) {                 // claim ranges
        int v = cnt[i];
        bse[i] = v ? atomicAdd(&cursor_b[i], v) : 0;
        cnt[i] = 0;
    }
    __syncthreads();
    #define PLACE1(sv, dv, tv)                                            \
        { int b_ = (dv) >> BSH;                                           \
          int r_ = atomicAdd(&cnt[b_], 1);                                \
          packed[bse[b_] + r_] = (u32)(sv) | ((u32)(tv) << 17)            \
                               | ((u32)((dv) & 127) << 21); }
    for (int e4 = start + t * 4; e4 < end; e4 += 1024) {  // place
        if (e4 + 3 < end) {
            int4 sv = *(const int4*)(ei + e4);
            int4 dv = *(const int4*)(dstp + e4);
            int4 tv = *(const int4*)(et + e4);
            PLACE1(sv.x, dv.x, tv.x);
            PLACE1(sv.y, dv.y, tv.y);
            PLACE1(sv.z, dv.z, tv.z);
            PLACE1(sv.w, dv.w, tv.w);
        } else {
            for (int e = e4; e < end; ++e) PLACE1(ei[e], dstp[e], et[e]);
        }
    }
    #undef PLACE1
}

// Pass B: fine sort; md gets src | rel<<20 | min(cnt,255)<<24.
__global__ __launch_bounds__(256) void bucket_sort(const u32* __restrict__ packed,
                                                   const int* __restrict__ bucket_base,
                                                   u32* __restrict__ md,
                                                   int* __restrict__ row_ptr, int N) {
    __shared__ int hist[FB];
    __shared__ int cbin[FB];
    __shared__ int ss[256];
    __shared__ u32 outb[CAPB];
    const int b = blockIdx.x, t = threadIdx.x;
    const int base = bucket_base[b];
    const int cnt = bucket_base[b + 1] - base;

    for (int i = t; i < FB; i += 256) hist[i] = 0;
    __syncthreads();
    for (int i = t; i < cnt; i += 256) {                   // fine histogram
        u32 p = packed[base + i];
        int f = (int)(((p >> 21) & 127u) * 16u + ((p >> 17) & 15u));
        atomicAdd(&hist[f], 1);
    }
    __syncthreads();
    int loc[8], s = 0;
    #pragma unroll
    for (int j = 0; j < 8; ++j) {
        loc[j] = hist[t * 8 + j]; s += loc[j];
        cbin[t * 8 + j] = loc[j];                          // keep counts
    }
    ss[t] = s; __syncthreads();
    for (int off = 1; off < 256; off <<= 1) {
        int tv = (t >= off) ? ss[t - off] : 0;
        __syncthreads();
        ss[t] += tv;
        __syncthreads();
    }
    int run = ss[t] - s;
    #pragma unroll
    for (int j = 0; j < 8; ++j) { hist[t * 8 + j] = run; run += loc[j]; }
    __syncthreads();
    if (t < 128) {                                         // row_ptr from scan
        int node = b * 128 + t;
        if (node < N) row_ptr[node] = base + hist[t * 16];
    }
    __syncthreads();
    for (int i = t; i < cnt; i += 256) {                   // place into staging
        u32 p = packed[base + i];
        int f = (int)(((p >> 21) & 127u) * 16u + ((p >> 17) & 15u));
        int pos = atomicAdd(&hist[f], 1);
        int cb = cbin[f]; if (cb > 255) cb = 255;
        u32 v = (p & 0x1FFFFu) | (((p >> 17) & 15u) << 20) | ((u32)cb << 24);
        if (pos < CAPB) outb[pos] = v;
        else            md[base + pos] = v;                // overflow fallback
    }
    __syncthreads();
    for (int i = t; i < cnt && i < CAPB; i += 256)         // coalesced stream-out
        md[base + i] = outb[i];
}

__global__ void convx_kernel(const float* __restrict__ x, us16* __restrict__ xb, int n4) {
    int i = blockIdx.x * 256 + threadIdx.x;    // n4 = N*HID/4
    if (i < n4) {
        float4 v = ((const float4*)x)[i];
        us16* o = xb + i * 4;
        o[0] = f2b(v.x); o[1] = f2b(v.y); o[2] = f2b(v.z); o[3] = f2b(v.w);
    }
}

// WcatT[l][h][k'], k' = r*RP+dd (dd<64 -> W, dd>=64 -> 0 pad), k'>=1088 -> root.
__global__ void convw_kernel(const float* __restrict__ W, const float* __restrict__ Wroot,
                             us16* __restrict__ WcatT, int total, int L) {
    int i = blockIdx.x * 256 + threadIdx.x;    // total = L*HID*KD2
    if (i < total) {
        int l = i / (HID * KD2);
        int rem = i % (HID * KD2);
        int h = rem / KD2, k = rem % KD2;
        float v = 0.f;
        if (k < NREL * RP) {
            int r = k / RP, dd = k % RP;
            if (dd < HID)
                v = W[(((size_t)l * NREL + r) * HID + dd) * HID + h];
        } else {
            int d = k - NREL * RP;
            v = Wroot[((size_t)l * HID + d) * HID + h];
        }
        WcatT[i] = f2b(v);
    }
}

// ---------- fused layer kernel ----------

// one S^T entry: weight bf16(1/cnt_j) if edge j has rel r and lies in [jlo,jhi)
__device__ __forceinline__ u32 onehot1(int j, u32 plw, int jlo, int jhi, int r) {
    u32 mv = (u32)__builtin_amdgcn_ds_bpermute((j & 63) << 2, (int)plw);
    int rel = (int)((mv >> 20) & 15u);
    float wv = __builtin_amdgcn_rcpf((float)(mv >> 24));
    u32 w16 = (u32)f2b(wv);
    bool sel = (j >= jlo) && (j < jhi) && (rel == r);
    return sel ? w16 : 0u;
}

__global__ __launch_bounds__(512, 6) void layer_kernel(
        const us16* __restrict__ x_in,        // bf16 [N,64]
        const int*  __restrict__ row_ptr,     // [N+1]
        const u32*  __restrict__ md,          // sorted: src | rel<<20 | cnt<<24
        const us16* __restrict__ WcatT,       // bf16 [64][1152] this layer
        const float* __restrict__ bias,       // fp32 [64] this layer
        us16* __restrict__ x_out,             // bf16 [N,64]  (if !last)
        float* __restrict__ out_f32,          // fp32 [N,64]  (if last)
        int flags, int N)                     // flags: 1=relu, 2=last
{
    __shared__ us16 Yt[64 * YSTR];            // 16896 B  (x rows, transposed)
    __shared__ us16 H[NPB * LSTR];            // 37120 B  -> 54016 total, 3 blk/CU
    const int tid = threadIdx.x, wave = tid >> 6, lane = tid & 63;
    const int l15 = lane & 15, quad = lane >> 4;
    const int node0 = blockIdx.x * NPB;

    const int blk_s = __builtin_amdgcn_readfirstlane(row_ptr[min(node0, N)]);
    const int blk_e = __builtin_amdgcn_readfirstlane(row_ptr[min(node0 + NPB, N)]);
    const int nch = (blk_e - blk_s + CHUNK - 1) / CHUNK;

    const int nqA = node0 + wave * 2;         // this wave's 2 nodes
    const int sA = __builtin_amdgcn_readfirstlane(row_ptr[min(nqA,     N)]);
    const int sB = __builtin_amdgcn_readfirstlane(row_ptr[min(nqA + 1, N)]);
    const int eB = __builtin_amdgcn_readfirstlane(row_ptr[min(nqA + 2, N)]);

    f32x4 accA[4] = {{0,0,0,0},{0,0,0,0},{0,0,0,0},{0,0,0,0}};
    f32x4 accB[4] = {{0,0,0,0},{0,0,0,0},{0,0,0,0},{0,0,0,0}};

    for (int c = 0; c < nch; ++c) {
        const int c0 = blk_s + c * CHUNK;
        const int cs = min(CHUNK, blk_e - c0);

        u32 pl0 = (lane < cs) ? md[c0 + lane] : 0u;
        u32 pl1 = (64 + lane < cs) ? md[c0 + 64 + lane] : 0u;

        // ---- stage A: raw-copy 16 edge rows (this wave) into Yt ----
        {
            u32 plw = (wave < 4) ? pl0 : pl1;
            const int rbase = (wave & 3) * 16;
            u32 hv[16];
            #pragma unroll
            for (int i = 0; i < 16; ++i) {       // 16 independent line loads
                u32 m = (u32)__builtin_amdgcn_readlane((int)plw, rbase + i);
                hv[i] = (u32)x_in[(size_t)(m & 0x1FFFFu) * HID + lane];
            }
            const int le0 = wave * 16;
            #pragma unroll
            for (int i = 0; i < 16; i += 2) {    // paired b32 writes, zero tail
                u32 y0 = (le0 + i     < cs) ? hv[i]     : 0u;
                u32 y1 = (le0 + i + 1 < cs) ? hv[i + 1] : 0u;
                *(u32*)(Yt + lane * YSTR + le0 + i) = y0 | (y1 << 16);
            }
        }
        __syncthreads();

        // ---- stage B: H^T += Yt @ S^T per node (4 MFMAs per 32-edge window) ----
        {
            // node A
            int jlo = max(sA - c0, 0), jhi = min(eB - c0, cs);   // full 2-node span unused; per node below
            int jloA = max(sA - c0, 0), jhiA = min(sB - c0, cs);
            int jloB = max(sB - c0, 0), jhiB = min(eB - c0, cs);
            (void)jlo; (void)jhi;
            #pragma unroll 1
            for (int sel = 0; sel < 2; ++sel) {
                int lo = sel ? jloB : jloA;
                int hi = sel ? jhiB : jhiA;
                if (hi <= lo) continue;
                f32x4* acc = sel ? accB : accA;
                for (int w = (lo >> 5); w <= ((hi - 1) >> 5); ++w) {
                    u32 plw = (w < 2) ? pl0 : pl1;
                    const int jb = w * 32 + quad * 8;
                    u32 bfr[4];
                    #pragma unroll
                    for (int t2 = 0; t2 < 4; ++t2) {
                        u32 loh = onehot1(jb + 2 * t2,     plw, lo, hi, l15);
                        u32 hih = onehot1(jb + 2 * t2 + 1, plw, lo, hi, l15);
                        bfr[t2] = loh | (hih << 16);
                    }
                    union { u32 u[4]; bf16x8 v; } B; 
                    B.u[0] = bfr[0]; B.u[1] = bfr[1]; B.u[2] = bfr[2]; B.u[3] = bfr[3];
                    #pragma unroll
                    for (int t = 0; t < 4; ++t) {
                        const us16* ap = Yt + (t * 16 + l15) * YSTR + w * 32 + quad * 8;
                        uint2 a0 = *(const uint2*)ap;
                        uint2 a1 = *(const uint2*)(ap + 4);
                        union { u32 u[4]; bf16x8 v; } A;
                        A.u[0] = a0.x; A.u[1] = a0.y; A.u[2] = a1.x; A.u[3] = a1.y;
                        acc[t] = __builtin_amdgcn_mfma_f32_16x16x32_bf16(A.v, B.v, acc[t], 0, 0, 0);
                    }
                }
            }
        }
        __syncthreads();
    }

    // ---- flush H: D rows=hid, cols=rel; plus root x and rel-pad zeros ----
    {
        #pragma unroll
        for (int sel = 0; sel < 2; ++sel) {
            int node = nqA + sel;
            us16* Hb = H + (wave * 2 + sel) * LSTR;
            const f32x4* acc = sel ? accB : accA;
            #pragma unroll
            for (int t = 0; t < 4; ++t) {
                u32 p0, p1;
                asm("v_cvt_pk_bf16_f32 %0, %1, %2" : "=v"(p0) : "v"(acc[t][0]), "v"(acc[t][1]));
                asm("v_cvt_pk_bf16_f32 %0, %1, %2" : "=v"(p1) : "v"(acc[t][2]), "v"(acc[t][3]));
                uint2 pk; pk.x = p0; pk.y = p1;
                *(uint2*)(Hb + l15 * RP + t * 16 + quad * 4) = pk;
            }
            Hb[NREL * RP + lane] = (node < N) ? x_in[(size_t)node * HID + lane] : (us16)0;
            if (lane < 16) {                   // zero dd in [64,68) per rel
                uint2 z; z.x = 0; z.y = 0;
                *(uint2*)(Hb + lane * RP + 64) = z;
            }
        }
    }
    __syncthreads();

    // ---- phase 2 (waves 0-3): [H|x] @ Wcat ----
    if (wave < 4) {
        f32x4 acc = {0.f, 0.f, 0.f, 0.f};
        const us16* Abase = H + l15 * LSTR + quad * 8;                          // A[m][k]
        const us16* Bbase = WcatT + (size_t)(wave * 16 + l15) * KD2 + quad * 8; // B[k][n]^T
        #pragma unroll 2
        for (int ks = 0; ks < KD2 / 32; ++ks) {
            bf16x8 af = *(const bf16x8*)(Abase + ks * 32);
            bf16x8 bf = *(const bf16x8*)(Bbase + ks * 32);
            acc = __builtin_amdgcn_mfma_f32_16x16x32_bf16(af, bf, acc, 0, 0, 0);
        }

        int col = wave * 16 + l15;
        float bv = bias[col];
        #pragma unroll
        for (int ri = 0; ri < 4; ++ri) {
            int nl = quad * 4 + ri, node = node0 + nl;  // C/D: col=lane&15, row=quad*4+ri
            if (node < N) {
                float v = acc[ri] + bv;
                if (flags & 1) v = fmaxf(v, 0.f);
                if (flags & 2) out_f32[node * HID + col] = v;
                else           x_out [node * HID + col] = f2b(v);
            }
        }
    }
}

// ---------- host ----------

extern "C" void kernel_launch(void* const* d_in, const int* in_sizes, int n_in,
                              void* d_out, int out_size, void* d_ws, size_t ws_size,
                              hipStream_t stream) {
    const int*   edge_index = (const int*)  d_in[0];
    const int*   edge_type  = (const int*)  d_in[1];
    const float* node_emb   = (const float*)d_in[2];
    const float* W          = (const float*)d_in[3];
    const float* Wroot      = (const float*)d_in[4];
    const float* bias       = (const float*)d_in[5];
    float* out = (float*)d_out;

    const int E = in_sizes[1];
    const int N = in_sizes[2] / HID;
    const int L = in_sizes[5] / HID;

    char* p = (char*)d_ws;
    size_t off = 0;
    auto carve = [&](size_t bytes) {
        void* q = p + off;
        off = (off + bytes + 255) & ~(size_t)255;
        return q;
    };
    int*   counts_b    = (int*)  carve((size_t)NBKT * 4);
    int*   bucket_base = (int*)  carve((size_t)(NBKT + 1) * 4);
    int*   cursor_b    = (int*)  carve((size_t)NBKT * 4);
    int*   row_ptr     = (int*)  carve((size_t)(N + 1) * 4);
    u32*   packed      = (u32*)  carve((size_t)E * 4);
    u32*   md          = (u32*)  carve((size_t)E * 4);
    us16*  xb0         = (us16*) carve((size_t)N * HID * 2);
    us16*  xb1         = (us16*) carve((size_t)N * HID * 2);
    us16*  WcatT       = (us16*) carve((size_t)L * HID * KD2 * 2);
    (void)ws_size; (void)n_in; (void)out_size;

    hipMemsetAsync(counts_b, 0, (size_t)NBKT * 4, stream);

    const int nblkA = (E + CHA - 1) / CHA;
    bucket_count<<<nblkA, 256, 0, stream>>>(edge_index, counts_b, E);
    scan_buckets<<<1, NBKT, 0, stream>>>(counts_b, bucket_base, cursor_b, row_ptr, N, E);
    bucket_place<<<nblkA, 256, 0, stream>>>(edge_index, edge_type, cursor_b, packed, E);
    bucket_sort<<<(N + 127) / 128, 256, 0, stream>>>(packed, bucket_base, md, row_ptr, N);

    convx_kernel<<<(N * HID / 4 + 255) / 256, 256, 0, stream>>>(node_emb, xb0, N * HID / 4);
    int wtot = L * HID * KD2;
    convw_kernel<<<(wtot + 255) / 256, 256, 0, stream>>>(W, Wroot, WcatT, wtot, L);

    int gl = (N + NPB - 1) / NPB;
    us16* xin = xb0;
    us16* xother = xb1;
    for (int l = 0; l < L; ++l) {
        int last = (l == L - 1);
        int flags = (last ? 2 : 1);
        layer_kernel<<<gl, 512, 0, stream>>>(
            xin, row_ptr, md,
            WcatT + (size_t)l * HID * KD2, bias + (size_t)l * HID,
            last ? nullptr : xother, last ? out : nullptr,
            flags, N);
        us16* t = xin; xin = xother; xother = t;
    }
}

// Round 7
// 569.306 us; speedup vs baseline: 1.4068x; 1.4068x over previous
//
#include <hip/hip_runtime.h>

// RGCN, 3 layers. N=100000, E=1.6M, R=16, HID=64.
// Edges sorted by (dst,rel) via two-level LDS-bucketed sort (passes A/B).
// md = src | rel<<20 (one u32/edge).
// Layer kernel (R1 structure + work-stealing): 512-thread blocks (8 waves),
// 16 nodes/block. Phase 1: waves CLAIM nodes from an LDS queue (1 node at a
// time, next node's md-window + root-row prefetched during current node's
// processing). Fixes the Poisson(32) per-wave tail: block phase-1 ends at
// max over 8 waves (~1.38x mean with static 2-nodes/wave; ~1.1x stealing).
// Run-length fp32 register accumulation per (node,rel) segment, metadata
// scalarized (readlane -> SGPR), 16-deep gather batches. bf16 flush to LDS
// H[16][1096]. Phase 2 (waves 0-3): out = [H|x] @ Wcat via
// mfma_f32_16x16x32_bf16 (K=1088).

#define HID   64
#define NREL  16
#define KD    1088          // NREL*HID + HID (root x appended as extra K)
#define NPB   16            // nodes per block (= MFMA M)
#define LSTR  1096          // LDS row stride (pad 1088 -> 1096)

#define NBKT  1024          // coarse buckets (dst>>7); requires N <= 131072
#define BSH   7             // bucket shift: 128 nodes per bucket
#define FB    2048          // fine bins per bucket: 128 nodes * 16 rels
#define CAPB  4096          // LDS staging capacity (avg bucket = 2048 edges)
#define CHA   8192          // edges per coarse-pass block

typedef __attribute__((ext_vector_type(8))) short bf16x8;
typedef __attribute__((ext_vector_type(4))) float f32x4;
typedef unsigned short us16;
typedef unsigned int u32;

__device__ __forceinline__ float b2f(us16 u) {
    union { u32 i; float f; } c; c.i = ((u32)u) << 16; return c.f;
}
__device__ __forceinline__ us16 f2b(float f) {   // round-to-nearest-even
    union { float f; u32 i; } c; c.f = f;
    u32 x = c.i;
    return (us16)((x + 0x7FFFu + ((x >> 16) & 1u)) >> 16);
}

// ---------- setup: two-level bucket sort by (dst,rel) ----------

// Pass A0: coarse bucket counts via per-block LDS histogram.
__global__ __launch_bounds__(256) void bucket_count(const int* __restrict__ ei,
                                                    int* __restrict__ counts_b, int E) {
    __shared__ int h[NBKT];
    const int t = threadIdx.x;
    for (int i = t; i < NBKT; i += 256) h[i] = 0;
    __syncthreads();
    const int* dstp = ei + E;
    int start = blockIdx.x * CHA, end = min(start + CHA, E);
    for (int e4 = start + t * 4; e4 < end; e4 += 1024) {
        if (e4 + 3 < end) {
            int4 d = *(const int4*)(dstp + e4);
            atomicAdd(&h[d.x >> BSH], 1);
            atomicAdd(&h[d.y >> BSH], 1);
            atomicAdd(&h[d.z >> BSH], 1);
            atomicAdd(&h[d.w >> BSH], 1);
        } else {
            for (int e = e4; e < end; ++e) atomicAdd(&h[dstp[e] >> BSH], 1);
        }
    }
    __syncthreads();
    for (int i = t; i < NBKT; i += 256) {
        int v = h[i];
        if (v) atomicAdd(&counts_b[i], v);
    }
}

// Exclusive scan of the 1024 bucket counts (single block).
__global__ __launch_bounds__(NBKT) void scan_buckets(const int* __restrict__ counts_b,
                                                     int* __restrict__ bucket_base,
                                                     int* __restrict__ cursor_b,
                                                     int* __restrict__ row_ptr,
                                                     int N, int E) {
    __shared__ int s[NBKT];
    int t = threadIdx.x;
    int v = counts_b[t];
    s[t] = v; __syncthreads();
    for (int off = 1; off < NBKT; off <<= 1) {
        int tv = (t >= off) ? s[t - off] : 0;
        __syncthreads();
        s[t] += tv;
        __syncthreads();
    }
    int ex = s[t] - v;
    bucket_base[t] = ex;
    cursor_b[t] = ex;
    if (t == NBKT - 1) bucket_base[NBKT] = ex + v;
    if (t == 0) row_ptr[N] = E;
}

// Pass A1: place edges into coarse buckets; per-bucket runs are contiguous
// per block, so global writes coalesce. packed = src | rel<<17 | dstlow<<21.
__global__ __launch_bounds__(256) void bucket_place(const int* __restrict__ ei,
                                                    const int* __restrict__ et,
                                                    int* __restrict__ cursor_b,
                                                    u32* __restrict__ packed, int E) {
    __shared__ int cnt[NBKT];
    __shared__ int bse[NBKT];
    const int t = threadIdx.x;
    for (int i = t; i < NBKT; i += 256) cnt[i] = 0;
    __syncthreads();
    const int* dstp = ei + E;
    int start = blockIdx.x * CHA, end = min(start + CHA, E);
    for (int e4 = start + t * 4; e4 < end; e4 += 1024) {  // count
        if (e4 + 3 < end) {
            int4 d = *(const int4*)(dstp + e4);
            atomicAdd(&cnt[d.x >> BSH], 1);
            atomicAdd(&cnt[d.y >> BSH], 1);
            atomicAdd(&cnt[d.z >> BSH], 1);
            atomicAdd(&cnt[d.w >> BSH], 1);
        } else {
            for (int e = e4; e < end; ++e) atomicAdd(&cnt[dstp[e] >> BSH], 1);
        }
    }
    __syncthreads();
    for (int i = t; i < NBKT; i += 256) {                 // claim ranges
        int v = cnt[i];
        bse[i] = v ? atomicAdd(&cursor_b[i], v) : 0;
        cnt[i] = 0;
    }
    __syncthreads();
    #define PLACE1(sv, dv, tv)                                            \
        { int b_ = (dv) >> BSH;                                           \
          int r_ = atomicAdd(&cnt[b_], 1);                                \
          packed[bse[b_] + r_] = (u32)(sv) | ((u32)(tv) << 17)            \
                               | ((u32)((dv) & 127) << 21); }
    for (int e4 = start + t * 4; e4 < end; e4 += 1024) {  // place
        if (e4 + 3 < end) {
            int4 sv = *(const int4*)(ei + e4);
            int4 dv = *(const int4*)(dstp + e4);
            int4 tv = *(const int4*)(et + e4);
            PLACE1(sv.x, dv.x, tv.x);
            PLACE1(sv.y, dv.y, tv.y);
            PLACE1(sv.z, dv.z, tv.z);
            PLACE1(sv.w, dv.w, tv.w);
        } else {
            for (int e = e4; e < end; ++e) PLACE1(ei[e], dstp[e], et[e]);
        }
    }
    #undef PLACE1
}

// Pass B: fine sort within each bucket by (dstlow,rel); emits md (coalesced
// via LDS staging) and row_ptr (from the in-LDS exclusive scan).
__global__ __launch_bounds__(256) void bucket_sort(const u32* __restrict__ packed,
                                                   const int* __restrict__ bucket_base,
                                                   u32* __restrict__ md,
                                                   int* __restrict__ row_ptr, int N) {
    __shared__ int hist[FB];
    __shared__ int ss[256];
    __shared__ u32 outb[CAPB];
    const int b = blockIdx.x, t = threadIdx.x;
    const int base = bucket_base[b];
    const int cnt = bucket_base[b + 1] - base;

    for (int i = t; i < FB; i += 256) hist[i] = 0;
    __syncthreads();
    for (int i = t; i < cnt; i += 256) {                   // fine histogram
        u32 p = packed[base + i];
        int f = (int)(((p >> 21) & 127u) * 16u + ((p >> 17) & 15u));
        atomicAdd(&hist[f], 1);
    }
    __syncthreads();
    // exclusive scan of 2048 bins: 8 bins/thread + block scan of per-thread sums
    int loc[8], s = 0;
    #pragma unroll
    for (int j = 0; j < 8; ++j) { loc[j] = hist[t * 8 + j]; s += loc[j]; }
    ss[t] = s; __syncthreads();
    for (int off = 1; off < 256; off <<= 1) {
        int tv = (t >= off) ? ss[t - off] : 0;
        __syncthreads();
        ss[t] += tv;
        __syncthreads();
    }
    int run = ss[t] - s;
    #pragma unroll
    for (int j = 0; j < 8; ++j) { hist[t * 8 + j] = run; run += loc[j]; }
    __syncthreads();
    if (t < 128) {                                         // row_ptr from scan
        int node = b * 128 + t;
        if (node < N) row_ptr[node] = base + hist[t * 16];
    }
    __syncthreads();
    for (int i = t; i < cnt; i += 256) {                   // place into staging
        u32 p = packed[base + i];
        int f = (int)(((p >> 21) & 127u) * 16u + ((p >> 17) & 15u));
        int pos = atomicAdd(&hist[f], 1);
        u32 v = (p & 0x1FFFFu) | (((p >> 17) & 15u) << 20);
        if (pos < CAPB) outb[pos] = v;
        else            md[base + pos] = v;                // overflow fallback
    }
    __syncthreads();
    for (int i = t; i < cnt && i < CAPB; i += 256)         // coalesced stream-out
        md[base + i] = outb[i];
}

__global__ void convx_kernel(const float* __restrict__ x, us16* __restrict__ xb, int n4) {
    int i = blockIdx.x * 256 + threadIdx.x;    // n4 = N*HID/4
    if (i < n4) {
        float4 v = ((const float4*)x)[i];
        us16* o = xb + i * 4;
        o[0] = f2b(v.x); o[1] = f2b(v.y); o[2] = f2b(v.z); o[3] = f2b(v.w);
    }
}

// WcatT[l][h][k], k = r*64+d for k<1024, else root d = k-1024.  bf16.
__global__ void convw_kernel(const float* __restrict__ W, const float* __restrict__ Wroot,
                             us16* __restrict__ WcatT, int total, int L) {
    int i = blockIdx.x * 256 + threadIdx.x;    // total = L*HID*KD
    if (i < total) {
        int l = i / (HID * KD);
        int rem = i % (HID * KD);
        int h = rem / KD, k = rem % KD;
        float v;
        if (k < NREL * HID) {
            int r = k >> 6, d = k & 63;
            v = W[(((size_t)l * NREL + r) * HID + d) * HID + h];
        } else {
            int d = k - NREL * HID;
            v = Wroot[((size_t)l * HID + d) * HID + h];
        }
        WcatT[i] = f2b(v);
    }
}

// ---------- fused layer kernel ----------

// consume edges [c0, wcnt) of a 64-edge metadata window held in p_l
__device__ __forceinline__ void proc_window(
        u32 p_l, int c0, int wcnt, const us16* __restrict__ x_in, us16* Hrow, int lane,
        float& acc, int& runlen, int& prev, u32& mask)
{
    #pragma unroll 1
    for (int c = c0; c < wcnt; c += 16) {
        us16 hv[16]; int pe[16];
        #pragma unroll
        for (int j = 0; j < 16; ++j) {           // 16 independent saddr gathers
            int idx = c + j; if (idx >= wcnt) idx = wcnt - 1;
            pe[j] = __builtin_amdgcn_readlane((int)p_l, idx);        // -> SGPR
            hv[j] = x_in[((u32)pe[j] & 0xFFFFFu) * HID + lane];
        }
        int m = wcnt - c; if (m > 16) m = 16;
        #pragma unroll
        for (int j = 0; j < 16; ++j) {
            if (j < m) {                          // scalar bound
                int r = (int)(((u32)pe[j]) >> 20);                   // SALU
                if (r != prev) {                  // s_cmp + s_cbranch
                    if (prev >= 0) {
                        Hrow[(prev << 6) + lane] =
                            f2b(acc * __builtin_amdgcn_rcpf((float)runlen));
                        mask |= 1u << prev;
                    }
                    prev = r; acc = 0.f; runlen = 0;
                }
                acc += b2f(hv[j]); ++runlen;
            }
        }
    }
}

__global__ __launch_bounds__(512, 8) void layer_kernel(
        const us16* __restrict__ x_in,        // bf16 [N,64]
        const int*  __restrict__ row_ptr,     // [N+1]
        const u32*  __restrict__ md,          // sorted by (dst,rel): src | rel<<20
        const us16* __restrict__ WcatT,       // bf16 [64][1088] this layer
        const float* __restrict__ bias,       // fp32 [64] this layer
        us16* __restrict__ x_out,             // bf16 [N,64]  (if !last)
        float* __restrict__ out_f32,          // fp32 [N,64]  (if last)
        int flags, int N)                     // flags: 1=relu, 2=last
{
    __shared__ us16 H[NPB * LSTR];            // 35072 B -> 4 blocks/CU (32 waves)
    __shared__ int rp_s[NPB + 1];
    __shared__ int qctr;
    const int tid = threadIdx.x, wave = tid >> 6, lane = tid & 63;
    const int node0 = blockIdx.x * NPB;

    if (tid <= NPB) rp_s[tid] = row_ptr[min(node0 + tid, N)];
    if (tid == 0) qctr = 0;
    __syncthreads();

    // ---- phase 1: work-stealing over the block's 16 nodes ----
    // claim-ahead pipeline: next node's md window + root row load during
    // current node's processing.
    {
        // claim slot A
        int cA = 0;
        if (lane == 0) cA = atomicAdd(&qctr, 1);
        cA = __shfl(cA, 0);
        int sA = 0, eA = 0; u32 plA = 0; us16 xrA = 0;
        if (cA < NPB) {
            sA = rp_s[cA]; eA = rp_s[cA + 1];
            sA = __builtin_amdgcn_readfirstlane(sA);
            eA = __builtin_amdgcn_readfirstlane(eA);
            int cnt = eA - sA;
            plA = (lane < cnt) ? md[sA + lane] : 0;
            xrA = (node0 + cA < N) ? x_in[(size_t)(node0 + cA) * HID + lane] : (us16)0;
        }

        while (cA < NPB) {
            // claim + prefetch slot B while A is hot
            int cB = 0;
            if (lane == 0) cB = atomicAdd(&qctr, 1);
            cB = __shfl(cB, 0);
            int sB = 0, eB = 0; u32 plB = 0; us16 xrB = 0;
            if (cB < NPB) {
                sB = rp_s[cB]; eB = rp_s[cB + 1];
                sB = __builtin_amdgcn_readfirstlane(sB);
                eB = __builtin_amdgcn_readfirstlane(eB);
                int cnt = eB - sB;
                plB = (lane < cnt) ? md[sB + lane] : 0;
                xrB = (node0 + cB < N) ? x_in[(size_t)(node0 + cB) * HID + lane] : (us16)0;
            }

            // ---- process node at slot A ----
            if (node0 + cA < N) {
                int start = sA, cnt = eA - sA;
                us16* Hrow = H + cA * LSTR;
                Hrow[NREL * HID + lane] = xrA;    // root/x columns

                float acc = 0.f;
                int runlen = 0, prev = -1;
                u32 mask = 0;

                proc_window(plA, 0, min(cnt, 64), x_in, Hrow, lane,
                            acc, runlen, prev, mask);
                for (int w0 = 64; w0 < cnt; w0 += 64) {    // rare overflow windows
                    int wcnt = min(64, cnt - w0);
                    u32 p2 = (lane < wcnt) ? md[start + w0 + lane] : 0;
                    proc_window(p2, 0, wcnt, x_in, Hrow, lane,
                                acc, runlen, prev, mask);
                }
                if (prev >= 0) {
                    Hrow[(prev << 6) + lane] =
                        f2b(acc * __builtin_amdgcn_rcpf((float)runlen));
                    mask |= 1u << prev;
                }
                #pragma unroll
                for (int r = 0; r < NREL; ++r)
                    if (!(mask & (1u << r))) Hrow[(r << 6) + lane] = 0;
            }

            cA = cB; sA = sB; eA = eB; plA = plB; xrA = xrB;
        }
    }
    __syncthreads();

    // ---- phase 2 (waves 0-3): [H|x] @ Wcat ----
    if (wave < 4) {
        const int n16 = lane & 15, quad = lane >> 4;
        f32x4 acc = {0.f, 0.f, 0.f, 0.f};
        const us16* Abase = H + n16 * LSTR + quad * 8;                         // A[m][k]
        const us16* Bbase = WcatT + (size_t)(wave * 16 + n16) * KD + quad * 8; // B[k][n]^T
        #pragma unroll 2
        for (int ks = 0; ks < KD / 32; ++ks) {
            bf16x8 af = *(const bf16x8*)(Abase + ks * 32);
            bf16x8 bf = *(const bf16x8*)(Bbase + ks * 32);
            acc = __builtin_amdgcn_mfma_f32_16x16x32_bf16(af, bf, acc, 0, 0, 0);
        }

        int col = wave * 16 + n16;
        float bv = bias[col];
        #pragma unroll
        for (int ri = 0; ri < 4; ++ri) {
            int nl = quad * 4 + ri, node = node0 + nl;  // C/D: col=lane&15, row=quad*4+ri
            if (node < N) {
                float v = acc[ri] + bv;
                if (flags & 1) v = fmaxf(v, 0.f);
                if (flags & 2) out_f32[node * HID + col] = v;
                else           x_out [node * HID + col] = f2b(v);
            }
        }
    }
}

// ---------- host ----------

extern "C" void kernel_launch(void* const* d_in, const int* in_sizes, int n_in,
                              void* d_out, int out_size, void* d_ws, size_t ws_size,
                              hipStream_t stream) {
    const int*   edge_index = (const int*)  d_in[0];
    const int*   edge_type  = (const int*)  d_in[1];
    const float* node_emb   = (const float*)d_in[2];
    const float* W          = (const float*)d_in[3];
    const float* Wroot      = (const float*)d_in[4];
    const float* bias       = (const float*)d_in[5];
    float* out = (float*)d_out;

    const int E = in_sizes[1];
    const int N = in_sizes[2] / HID;
    const int L = in_sizes[5] / HID;

    char* p = (char*)d_ws;
    size_t off = 0;
    auto carve = [&](size_t bytes) {
        void* q = p + off;
        off = (off + bytes + 255) & ~(size_t)255;
        return q;
    };
    int*   counts_b    = (int*)  carve((size_t)NBKT * 4);
    int*   bucket_base = (int*)  carve((size_t)(NBKT + 1) * 4);
    int*   cursor_b    = (int*)  carve((size_t)NBKT * 4);
    int*   row_ptr     = (int*)  carve((size_t)(N + 1) * 4);
    u32*   packed      = (u32*)  carve((size_t)E * 4);
    u32*   md          = (u32*)  carve((size_t)E * 4);
    us16*  xb0         = (us16*) carve((size_t)N * HID * 2);
    us16*  xb1         = (us16*) carve((size_t)N * HID * 2);
    us16*  WcatT       = (us16*) carve((size_t)L * HID * KD * 2);
    (void)ws_size; (void)n_in; (void)out_size;

    hipMemsetAsync(counts_b, 0, (size_t)NBKT * 4, stream);

    const int nblkA = (E + CHA - 1) / CHA;
    bucket_count<<<nblkA, 256, 0, stream>>>(edge_index, counts_b, E);
    scan_buckets<<<1, NBKT, 0, stream>>>(counts_b, bucket_base, cursor_b, row_ptr, N, E);
    bucket_place<<<nblkA, 256, 0, stream>>>(edge_index, edge_type, cursor_b, packed, E);
    bucket_sort<<<(N + 127) / 128, 256, 0, stream>>>(packed, bucket_base, md, row_ptr, N);

    convx_kernel<<<(N * HID / 4 + 255) / 256, 256, 0, stream>>>(node_emb, xb0, N * HID / 4);
    int wtot = L * HID * KD;
    convw_kernel<<<(wtot + 255) / 256, 256, 0, stream>>>(W, Wroot, WcatT, wtot, L);

    int gl = (N + NPB - 1) / NPB;
    us16* xin = xb0;
    us16* xother = xb1;
    for (int l = 0; l < L; ++l) {
        int last = (l == L - 1);
        int flags = (last ? 2 : 1);
        layer_kernel<<<gl, 512, 0, stream>>>(
            xin, row_ptr, md,
            WcatT + (size_t)l * HID * KD, bias + (size_t)l * HID,
            last ? nullptr : xother, last ? out : nullptr,
            flags, N);
        us16* t = xin; xin = xother; xother = t;
    }
}

// Round 8
// 523.714 us; speedup vs baseline: 1.5293x; 1.0871x over previous
//
#include <hip/hip_runtime.h>

// RGCN, 3 layers. N=100000, E=1.6M, R=16, HID=64.
// Edges sorted by (dst,rel) via two-level LDS-bucketed sort:
//   pass A (bucket_place): coarse bucket by dst>>7; per-block LDS histogram
//     + one global cursor claim per (block,bucket); writes into a SPARSE
//     per-bucket region (b*BCAP + offset) -> no pre-count pass needed.
//   scan_buckets: exclusive scan of the 1024 post-place bucket counts.
//   pass B (bucket_sort): one block per bucket (~2048 edges): LDS histogram
//     over 2048 (dstlow,rel) fine keys, in-LDS scan, row_ptr emitted,
//     md compacted sparse->dense, streamed out coalesced via LDS staging.
// md = src | rel<<20 (one u32/edge).
// Layer kernel (R1-best, 139us; R2-R7 variants all slower -> phase 1 is at
// the chip's random-128B-line service ceiling ~4.8 lines/cy): 512-thread
// blocks (8 waves), 16 nodes/block, 2 nodes/wave. Phase 1: run-length fp32
// register accumulation per (node,rel) segment, metadata scalarized
// (readlane -> SGPR, SALU run detection), 16-deep gather batches. bf16
// flush to LDS H[16][1096]. Phase 2 (waves 0-3): out = [H|x] @ Wcat via
// mfma_f32_16x16x32_bf16 (K=1088).

#define HID   64
#define NREL  16
#define KD    1088          // NREL*HID + HID (root x appended as extra K)
#define NPB   16            // nodes per block (= MFMA M)
#define NPW   2             // nodes per wave (8 waves)
#define LSTR  1096          // LDS row stride (pad 1088 -> 1096)

#define NBKT  1024          // coarse buckets (dst>>7); requires N <= 131072
#define BSH   7             // bucket shift: 128 nodes per bucket
#define BCAP  4096          // sparse per-bucket capacity (mean 2048, sd ~45)
#define FB    2048          // fine bins per bucket: 128 nodes * 16 rels
#define CAPB  4096          // LDS staging capacity in bucket_sort
#define CHA   8192          // edges per coarse-pass block

typedef __attribute__((ext_vector_type(8))) short bf16x8;
typedef __attribute__((ext_vector_type(4))) float f32x4;
typedef unsigned short us16;
typedef unsigned int u32;

__device__ __forceinline__ float b2f(us16 u) {
    union { u32 i; float f; } c; c.i = ((u32)u) << 16; return c.f;
}
__device__ __forceinline__ us16 f2b(float f) {   // round-to-nearest-even
    union { float f; u32 i; } c; c.f = f;
    u32 x = c.i;
    return (us16)((x + 0x7FFFu + ((x >> 16) & 1u)) >> 16);
}

// ---------- setup: two-level bucket sort by (dst,rel) ----------

// Pass A: place edges into sparse coarse buckets; per-bucket runs are
// contiguous per block, so global writes coalesce.
// packed = src | rel<<17 | dstlow<<21.
__global__ __launch_bounds__(256) void bucket_place(const int* __restrict__ ei,
                                                    const int* __restrict__ et,
                                                    int* __restrict__ cursor_b,
                                                    u32* __restrict__ packed, int E) {
    __shared__ int cnt[NBKT];
    __shared__ int bse[NBKT];
    const int t = threadIdx.x;
    for (int i = t; i < NBKT; i += 256) cnt[i] = 0;
    __syncthreads();
    const int* dstp = ei + E;
    int start = blockIdx.x * CHA, end = min(start + CHA, E);
    for (int e4 = start + t * 4; e4 < end; e4 += 1024) {  // count
        if (e4 + 3 < end) {
            int4 d = *(const int4*)(dstp + e4);
            atomicAdd(&cnt[d.x >> BSH], 1);
            atomicAdd(&cnt[d.y >> BSH], 1);
            atomicAdd(&cnt[d.z >> BSH], 1);
            atomicAdd(&cnt[d.w >> BSH], 1);
        } else {
            for (int e = e4; e < end; ++e) atomicAdd(&cnt[dstp[e] >> BSH], 1);
        }
    }
    __syncthreads();
    for (int i = t; i < NBKT; i += 256) {                 // claim sparse ranges
        int v = cnt[i];
        bse[i] = v ? (i * BCAP + atomicAdd(&cursor_b[i], v)) : 0;
        cnt[i] = 0;
    }
    __syncthreads();
    #define PLACE1(sv, dv, tv)                                            \
        { int b_ = (dv) >> BSH;                                           \
          int r_ = atomicAdd(&cnt[b_], 1);                                \
          packed[bse[b_] + r_] = (u32)(sv) | ((u32)(tv) << 17)            \
                               | ((u32)((dv) & 127) << 21); }
    for (int e4 = start + t * 4; e4 < end; e4 += 1024) {  // place
        if (e4 + 3 < end) {
            int4 sv = *(const int4*)(ei + e4);
            int4 dv = *(const int4*)(dstp + e4);
            int4 tv = *(const int4*)(et + e4);
            PLACE1(sv.x, dv.x, tv.x);
            PLACE1(sv.y, dv.y, tv.y);
            PLACE1(sv.z, dv.z, tv.z);
            PLACE1(sv.w, dv.w, tv.w);
        } else {
            for (int e = e4; e < end; ++e) PLACE1(ei[e], dstp[e], et[e]);
        }
    }
    #undef PLACE1
}

// Exclusive scan of the 1024 post-place bucket counts (single block).
__global__ __launch_bounds__(NBKT) void scan_buckets(const int* __restrict__ cursor_b,
                                                     int* __restrict__ bucket_base,
                                                     int* __restrict__ row_ptr,
                                                     int N, int E) {
    __shared__ int s[NBKT];
    int t = threadIdx.x;
    int v = cursor_b[t];
    s[t] = v; __syncthreads();
    for (int off = 1; off < NBKT; off <<= 1) {
        int tv = (t >= off) ? s[t - off] : 0;
        __syncthreads();
        s[t] += tv;
        __syncthreads();
    }
    int ex = s[t] - v;
    bucket_base[t] = ex;
    if (t == NBKT - 1) bucket_base[NBKT] = ex + v;
    if (t == 0) row_ptr[N] = E;
}

// Pass B: fine sort within each bucket by (dstlow,rel); reads sparse packed,
// emits dense md (coalesced via LDS staging) and row_ptr (from in-LDS scan).
__global__ __launch_bounds__(256) void bucket_sort(const u32* __restrict__ packed,
                                                   const int* __restrict__ bucket_base,
                                                   u32* __restrict__ md,
                                                   int* __restrict__ row_ptr, int N) {
    __shared__ int hist[FB];
    __shared__ int ss[256];
    __shared__ u32 outb[CAPB];
    const int b = blockIdx.x, t = threadIdx.x;
    const int base = bucket_base[b];
    const int cnt = bucket_base[b + 1] - base;
    const u32* pk = packed + (size_t)b * BCAP;

    for (int i = t; i < FB; i += 256) hist[i] = 0;
    __syncthreads();
    for (int i = t; i < cnt; i += 256) {                   // fine histogram
        u32 p = pk[i];
        int f = (int)(((p >> 21) & 127u) * 16u + ((p >> 17) & 15u));
        atomicAdd(&hist[f], 1);
    }
    __syncthreads();
    // exclusive scan of 2048 bins: 8 bins/thread + block scan of per-thread sums
    int loc[8], s = 0;
    #pragma unroll
    for (int j = 0; j < 8; ++j) { loc[j] = hist[t * 8 + j]; s += loc[j]; }
    ss[t] = s; __syncthreads();
    for (int off = 1; off < 256; off <<= 1) {
        int tv = (t >= off) ? ss[t - off] : 0;
        __syncthreads();
        ss[t] += tv;
        __syncthreads();
    }
    int run = ss[t] - s;
    #pragma unroll
    for (int j = 0; j < 8; ++j) { hist[t * 8 + j] = run; run += loc[j]; }
    __syncthreads();
    if (t < 128) {                                         // row_ptr from scan
        int node = b * 128 + t;
        if (node < N) row_ptr[node] = base + hist[t * 16];
    }
    __syncthreads();
    for (int i = t; i < cnt; i += 256) {                   // place into staging
        u32 p = pk[i];
        int f = (int)(((p >> 21) & 127u) * 16u + ((p >> 17) & 15u));
        int pos = atomicAdd(&hist[f], 1);
        u32 v = (p & 0x1FFFFu) | (((p >> 17) & 15u) << 20);
        if (pos < CAPB) outb[pos] = v;
        else            md[base + pos] = v;                // overflow fallback
    }
    __syncthreads();
    for (int i = t; i < cnt && i < CAPB; i += 256)         // coalesced stream-out
        md[base + i] = outb[i];
}

__global__ void convx_kernel(const float* __restrict__ x, us16* __restrict__ xb, int n4) {
    int i = blockIdx.x * 256 + threadIdx.x;    // n4 = N*HID/4
    if (i < n4) {
        float4 v = ((const float4*)x)[i];
        us16* o = xb + i * 4;
        o[0] = f2b(v.x); o[1] = f2b(v.y); o[2] = f2b(v.z); o[3] = f2b(v.w);
    }
}

// WcatT[l][h][k], k = r*64+d for k<1024, else root d = k-1024.  bf16.
__global__ void convw_kernel(const float* __restrict__ W, const float* __restrict__ Wroot,
                             us16* __restrict__ WcatT, int total, int L) {
    int i = blockIdx.x * 256 + threadIdx.x;    // total = L*HID*KD
    if (i < total) {
        int l = i / (HID * KD);
        int rem = i % (HID * KD);
        int h = rem / KD, k = rem % KD;
        float v;
        if (k < NREL * HID) {
            int r = k >> 6, d = k & 63;
            v = W[(((size_t)l * NREL + r) * HID + d) * HID + h];
        } else {
            int d = k - NREL * HID;
            v = Wroot[((size_t)l * HID + d) * HID + h];
        }
        WcatT[i] = f2b(v);
    }
}

// ---------- fused layer kernel (exact R1 structure, best measured) ----------

// consume edges [c0, wcnt) of a 64-edge metadata window held in p_l
__device__ __forceinline__ void proc_window(
        u32 p_l, int c0, int wcnt, const us16* __restrict__ x_in, us16* Hrow, int lane,
        float& acc, int& runlen, int& prev, u32& mask)
{
    #pragma unroll 1
    for (int c = c0; c < wcnt; c += 16) {
        us16 hv[16]; int pe[16];
        #pragma unroll
        for (int j = 0; j < 16; ++j) {           // 16 independent saddr gathers
            int idx = c + j; if (idx >= wcnt) idx = wcnt - 1;
            pe[j] = __builtin_amdgcn_readlane((int)p_l, idx);        // -> SGPR
            hv[j] = x_in[((u32)pe[j] & 0xFFFFFu) * HID + lane];
        }
        int m = wcnt - c; if (m > 16) m = 16;
        #pragma unroll
        for (int j = 0; j < 16; ++j) {
            if (j < m) {                          // scalar bound
                int r = (int)(((u32)pe[j]) >> 20);                   // SALU
                if (r != prev) {                  // s_cmp + s_cbranch
                    if (prev >= 0) {
                        Hrow[(prev << 6) + lane] =
                            f2b(acc * __builtin_amdgcn_rcpf((float)runlen));
                        mask |= 1u << prev;
                    }
                    prev = r; acc = 0.f; runlen = 0;
                }
                acc += b2f(hv[j]); ++runlen;
            }
        }
    }
}

__global__ __launch_bounds__(512, 8) void layer_kernel(
        const us16* __restrict__ x_in,        // bf16 [N,64]
        const int*  __restrict__ row_ptr,     // [N+1]
        const u32*  __restrict__ md,          // sorted by (dst,rel): src | rel<<20
        const us16* __restrict__ WcatT,       // bf16 [64][1088] this layer
        const float* __restrict__ bias,       // fp32 [64] this layer
        us16* __restrict__ x_out,             // bf16 [N,64]  (if !last)
        float* __restrict__ out_f32,          // fp32 [N,64]  (if last)
        int flags, int N)                     // flags: 1=relu, 2=last
{
    __shared__ us16 H[NPB * LSTR];            // 35072 B -> 4 blocks/CU (32 waves)
    const int tid = threadIdx.x, wave = tid >> 6, lane = tid & 63;
    const int node0 = blockIdx.x * NPB;
    const int nodeq = node0 + wave * NPW;

    // ---- phase 1 prologue: metadata windows + root-x rows in flight ----
    int rp[NPW + 1];
    #pragma unroll
    for (int i = 0; i <= NPW; ++i)
        rp[i] = __builtin_amdgcn_readfirstlane(row_ptr[min(nodeq + i, N)]);

    u32 pl[NPW]; us16 xr[NPW];
    #pragma unroll
    for (int q = 0; q < NPW; ++q) {
        int cnt = rp[q + 1] - rp[q];
        pl[q] = (lane < cnt) ? md[rp[q] + lane] : 0;
        xr[q] = (nodeq + q < N) ? x_in[(nodeq + q) * HID + lane] : (us16)0;
    }

    // ---- phase 1: consume node-serial per wave (2 nodes) ----
    #pragma unroll
    for (int q = 0; q < NPW; ++q) {
        int node = nodeq + q;
        if (node >= N) break;
        int start = rp[q], cnt = rp[q + 1] - start;
        us16* Hrow = H + (wave * NPW + q) * LSTR;
        Hrow[NREL * HID + lane] = xr[q];      // root/x columns

        float acc = 0.f;
        int runlen = 0, prev = -1;
        u32 mask = 0;

        proc_window(pl[q], 0, min(cnt, 64), x_in, Hrow, lane, acc, runlen, prev, mask);
        for (int w0 = 64; w0 < cnt; w0 += 64) {            // rare overflow windows
            int wcnt = min(64, cnt - w0);
            u32 p2 = (lane < wcnt) ? md[start + w0 + lane] : 0;
            proc_window(p2, 0, wcnt, x_in, Hrow, lane, acc, runlen, prev, mask);
        }
        if (prev >= 0) {
            Hrow[(prev << 6) + lane] = f2b(acc * __builtin_amdgcn_rcpf((float)runlen));
            mask |= 1u << prev;
        }
        #pragma unroll
        for (int r = 0; r < NREL; ++r)
            if (!(mask & (1u << r))) Hrow[(r << 6) + lane] = 0;
    }
    __syncthreads();

    // ---- phase 2 (waves 0-3): [H|x] @ Wcat ----
    if (wave < 4) {
        const int n16 = lane & 15, quad = lane >> 4;
        f32x4 acc = {0.f, 0.f, 0.f, 0.f};
        const us16* Abase = H + n16 * LSTR + quad * 8;                         // A[m][k]
        const us16* Bbase = WcatT + (size_t)(wave * 16 + n16) * KD + quad * 8; // B[k][n]^T
        #pragma unroll 2
        for (int ks = 0; ks < KD / 32; ++ks) {
            bf16x8 af = *(const bf16x8*)(Abase + ks * 32);
            bf16x8 bf = *(const bf16x8*)(Bbase + ks * 32);
            acc = __builtin_amdgcn_mfma_f32_16x16x32_bf16(af, bf, acc, 0, 0, 0);
        }

        int col = wave * 16 + n16;
        float bv = bias[col];
        #pragma unroll
        for (int ri = 0; ri < 4; ++ri) {
            int nl = quad * 4 + ri, node = node0 + nl;  // C/D: col=lane&15, row=quad*4+ri
            if (node < N) {
                float v = acc[ri] + bv;
                if (flags & 1) v = fmaxf(v, 0.f);
                if (flags & 2) out_f32[node * HID + col] = v;
                else           x_out [node * HID + col] = f2b(v);
            }
        }
    }
}

// ---------- host ----------

extern "C" void kernel_launch(void* const* d_in, const int* in_sizes, int n_in,
                              void* d_out, int out_size, void* d_ws, size_t ws_size,
                              hipStream_t stream) {
    const int*   edge_index = (const int*)  d_in[0];
    const int*   edge_type  = (const int*)  d_in[1];
    const float* node_emb   = (const float*)d_in[2];
    const float* W          = (const float*)d_in[3];
    const float* Wroot      = (const float*)d_in[4];
    const float* bias       = (const float*)d_in[5];
    float* out = (float*)d_out;

    const int E = in_sizes[1];
    const int N = in_sizes[2] / HID;
    const int L = in_sizes[5] / HID;

    char* p = (char*)d_ws;
    size_t off = 0;
    auto carve = [&](size_t bytes) {
        void* q = p + off;
        off = (off + bytes + 255) & ~(size_t)255;
        return q;
    };
    int*   cursor_b    = (int*)  carve((size_t)NBKT * 4);
    int*   bucket_base = (int*)  carve((size_t)(NBKT + 1) * 4);
    int*   row_ptr     = (int*)  carve((size_t)(N + 1) * 4);
    u32*   packed      = (u32*)  carve((size_t)NBKT * BCAP * 4);   // sparse
    u32*   md          = (u32*)  carve((size_t)E * 4);
    us16*  xb0         = (us16*) carve((size_t)N * HID * 2);
    us16*  xb1         = (us16*) carve((size_t)N * HID * 2);
    us16*  WcatT       = (us16*) carve((size_t)L * HID * KD * 2);
    (void)ws_size; (void)n_in; (void)out_size;

    hipMemsetAsync(cursor_b, 0, (size_t)NBKT * 4, stream);

    const int nblkA = (E + CHA - 1) / CHA;
    bucket_place<<<nblkA, 256, 0, stream>>>(edge_index, edge_type, cursor_b, packed, E);
    scan_buckets<<<1, NBKT, 0, stream>>>(cursor_b, bucket_base, row_ptr, N, E);
    bucket_sort<<<(N + 127) / 128, 256, 0, stream>>>(packed, bucket_base, md, row_ptr, N);

    convx_kernel<<<(N * HID / 4 + 255) / 256, 256, 0, stream>>>(node_emb, xb0, N * HID / 4);
    int wtot = L * HID * KD;
    convw_kernel<<<(wtot + 255) / 256, 256, 0, stream>>>(W, Wroot, WcatT, wtot, L);

    int gl = (N + NPB - 1) / NPB;
    us16* xin = xb0;
    us16* xother = xb1;
    for (int l = 0; l < L; ++l) {
        int last = (l == L - 1);
        int flags = (last ? 2 : 1);
        layer_kernel<<<gl, 512, 0, stream>>>(
            xin, row_ptr, md,
            WcatT + (size_t)l * HID * KD, bias + (size_t)l * HID,
            last ? nullptr : xother, last ? out : nullptr,
            flags, N);
        us16* t = xin; xin = xother; xother = t;
    }
}